// Round 2
// baseline (282.296 us; speedup 1.0000x reference)
//
#include <hip/hip_runtime.h>
#include <hip/hip_bf16.h>

typedef float floatx4 __attribute__((ext_vector_type(4)));
typedef short bhalf8  __attribute__((ext_vector_type(8)));
typedef unsigned short ush;

#define EPS 1e-5f

constexpr int Bb = 8, S = 256, T = 64, Dc = 100;
constexpr int SH = 255;   // conv2/y2 rows (S-H+1)
constexpr int SO = 254;   // final logit rows
constexpr int CK = 128;   // padded input-channel (K per h-tap)
constexpr int CR = 112;   // padded output-channel rows (7 x 16)
constexpr int LSTR = 136; // LDS row stride in bf16: 272B -> 2-way max bank conflict, 16B aligned

// workspace layout (bytes)
constexpr size_t OFF_S1  = 0;
constexpr size_t OFF_U1  = 512;
constexpr size_t OFF_S2  = 1024;
constexpr size_t OFF_U2  = 1536;
constexpr size_t OFF_W30 = 2048;
constexpr size_t OFF_W31 = 2560;
constexpr size_t OFF_AQB = 4096;                                 // f32 [8][255][128]
constexpr size_t OFF_AK  = OFF_AQB + (size_t)Bb * SH * CK * 4;   // f32 [8][256][128]
constexpr size_t OFF_W2P = OFF_AK + (size_t)Bb * S * CK * 4;     // bf16 [2][112][128]
constexpr size_t OFF_Z0  = OFF_W2P + (size_t)2 * CR * CK * 2;    // f32 [8][255][256]
constexpr size_t OFF_Z1  = OFF_Z0 + (size_t)Bb * SH * S * 4;     // f32 [8][255][256]

// ---------------- K1a: fold BN params into per-channel affine + W3 taps ----------------
__global__ void k_params(const float* g1, const float* be1,
                         const float* m1, const float* var1,
                         const float* b2, const float* g2,
                         const float* be2, const float* m2,
                         const float* var2, const float* W3,
                         float* S1, float* U1, float* S2, float* U2,
                         float* W30, float* W31) {
    int c = threadIdx.x;
    if (c >= CK) return;
    float s1 = 0.f, u1 = 0.f, s2 = 0.f, u2 = 0.f, w0 = 0.f, w1 = 0.f;
    if (c < Dc) {
        float sg1 = g1[c] / sqrtf(var1[c] + EPS);
        s1 = sg1;
        u1 = be1[c] - m1[c] * sg1;                        // y1 = ap*s1 + u1 (b1 folded into AqB)
        float sg2 = g2[c] / sqrtf(var2[c] + EPS);
        s2 = sg2;
        u2 = (b2[c] - m2[c]) * sg2 + be2[c];              // y2 = (acc+res)*s2 + u2
        w0 = W3[c * 2 + 0];
        w1 = W3[c * 2 + 1];
    }
    S1[c] = s1; U1[c] = u1; S2[c] = s2; U2[c] = u2; W30[c] = w0; W31[c] = w1;
}

// ---------------- K1b: pack W2 -> [h][c(112)][c'(128)] bf16, zero padded ----------------
__global__ void k_w2pack(const float* W2, ush* W2p) {
    int idx = blockIdx.x * 256 + threadIdx.x;   // exactly 2*112*128 = 28672 threads
    int h = idx / (CR * CK);
    int rem = idx % (CR * CK);
    int c = rem / CK, cp = rem % CK;
    __hip_bfloat16 val = __float2bfloat16(0.f);
    if (c < Dc && cp < Dc) val = __float2bfloat16(W2[((size_t)c * Dc + cp) * 2 + h]); // (O,I,H,1)
    W2p[idx] = *reinterpret_cast<ush*>(&val);
}

// ---------------- K1c: AqB[b][i][c] = sum_t q[b,i,t]W1[c,t,0] + q[b,i+1,t]W1[c,t,1] + b1[c]
__global__ __launch_bounds__(128) void k_aq(const float* q, const float* W1,
                                            const float* b1, float* AqB) {
    __shared__ float qs[128];
    int tid = threadIdx.x, i = blockIdx.x, b = blockIdx.y;
    if (tid < 64) qs[tid] = q[((size_t)b * S + i) * T + tid];
    else          qs[tid] = q[((size_t)b * S + i + 1) * T + (tid - 64)];
    __syncthreads();
    float s = 0.f;
    if (tid < Dc) {
        const float* wr = W1 + (size_t)tid * 256;   // W1[c][t][h], t in [0,64)
        #pragma unroll 8
        for (int t = 0; t < 64; ++t) {
            s = fmaf(qs[t],      wr[2 * t],     s);
            s = fmaf(qs[64 + t], wr[2 * t + 1], s);
        }
        s += b1[tid];
    }
    AqB[((size_t)b * SH + i) * CK + tid] = s;   // zeros for c >= 100
}

// ---------------- K1d: Ak[b][j][c] = sum_t k[b,j,t]*(W1[c,64+t,0]+W1[c,64+t,1]) ----------------
__global__ __launch_bounds__(128) void k_ak(const float* kin, const float* W1,
                                            float* Ak) {
    __shared__ float ks[64];
    int tid = threadIdx.x, j = blockIdx.x, b = blockIdx.y;
    if (tid < 64) ks[tid] = kin[((size_t)b * S + j) * T + tid];
    __syncthreads();
    float s = 0.f;
    if (tid < Dc) {
        const float* wr = W1 + (size_t)tid * 256 + 128;  // input channels 64..127
        #pragma unroll 8
        for (int t = 0; t < 64; ++t)
            s = fmaf(ks[t], wr[2 * t] + wr[2 * t + 1], s);
    }
    Ak[((size_t)b * S + j) * CK + tid] = s;
}

// ---------------- K3: fused y1->conv2->bn2->relu->conv3 taps. block=(jt, i', b) ----------------
// D[c][m] = sum_k W2[c][k] * relu(y1)[k][m], 16x16x32 bf16 MFMA, 2 h-phases.
__global__ __launch_bounds__(256) void k_main(const float* __restrict__ AqB, const float* __restrict__ Ak,
                                              const ush* __restrict__ W2p,
                                              const float* __restrict__ S1, const float* __restrict__ U1,
                                              const float* __restrict__ S2, const float* __restrict__ U2,
                                              const float* __restrict__ W30f, const float* __restrict__ W31f,
                                              float* __restrict__ Z0, float* __restrict__ Z1) {
    __shared__ __align__(16) ush Xs[128 * LSTR];   // relu(y1)[j_local][c'] for current h
    __shared__ __align__(16) ush W2s[CR * LSTR];   // W2[c][c'] for current h
    const int tid = threadIdx.x;
    const int wv = tid >> 6, lane = tid & 63, ln = lane & 15, quad = lane >> 4;
    const int jt = blockIdx.x, ip = blockIdx.y, b = blockIdx.z;
    const int j0 = jt << 7;

    floatx4 acc0[7], acc1[7];
    #pragma unroll
    for (int ct = 0; ct < 7; ++ct) {
        acc0[ct] = (floatx4){0.f, 0.f, 0.f, 0.f};
        acc1[ct] = (floatx4){0.f, 0.f, 0.f, 0.f};
    }

    for (int h = 0; h < 2; ++h) {
        __syncthreads();
        // stage W2 half (16B chunks)
        for (int idx = tid; idx < CR * 16; idx += 256) {
            int row = idx >> 4, ch = idx & 15;
            *reinterpret_cast<uint4*>(&W2s[row * LSTR + ch * 8]) =
                *reinterpret_cast<const uint4*>(&W2p[(h * CR + row) * CK + ch * 8]);
        }
        // stage relu(y1) for row i'' = ip + h; ap = AqB[i''-1] + Ak[j] (0 for padded row)
        const int i2 = ip + h;
        const float* aqrow = AqB + (size_t)(b * SH + (i2 - 1)) * CK;
        for (int idx = tid; idx < 128 * 32; idx += 256) {
            int jm = idx >> 5, c4 = idx & 31, c = c4 << 2;
            float a0 = 0.f, a1 = 0.f, a2 = 0.f, a3 = 0.f;
            if (i2 > 0) {
                const float4 aq = *reinterpret_cast<const float4*>(aqrow + c);
                const float4 ak = *reinterpret_cast<const float4*>(Ak + (size_t)(b * S + j0 + jm) * CK + c);
                a0 = aq.x + ak.x; a1 = aq.y + ak.y; a2 = aq.z + ak.z; a3 = aq.w + ak.w;
            }
            const float4 s1 = *reinterpret_cast<const float4*>(S1 + c);
            const float4 u1 = *reinterpret_cast<const float4*>(U1 + c);
            float y0 = fmaxf(fmaf(a0, s1.x, u1.x), 0.f);
            float y1 = fmaxf(fmaf(a1, s1.y, u1.y), 0.f);
            float y2 = fmaxf(fmaf(a2, s1.z, u1.z), 0.f);
            float y3 = fmaxf(fmaf(a3, s1.w, u1.w), 0.f);
            __hip_bfloat162 p01 = __float22bfloat162_rn(make_float2(y0, y1));
            __hip_bfloat162 p23 = __float22bfloat162_rn(make_float2(y2, y3));
            *reinterpret_cast<__hip_bfloat162*>(&Xs[jm * LSTR + c]) = p01;
            *reinterpret_cast<__hip_bfloat162*>(&Xs[jm * LSTR + c + 2]) = p23;
        }
        __syncthreads();
        // K loop: 4 ksteps of 32; each wave covers 32 m-columns (amortizes A-frag reads)
        #pragma unroll
        for (int ks = 0; ks < 4; ++ks) {
            const int k0 = ks * 32 + quad * 8;
            const bhalf8 bf0 = *reinterpret_cast<const bhalf8*>(&Xs[(wv * 32 + ln) * LSTR + k0]);
            const bhalf8 bf1 = *reinterpret_cast<const bhalf8*>(&Xs[(wv * 32 + 16 + ln) * LSTR + k0]);
            #pragma unroll
            for (int ct = 0; ct < 7; ++ct) {
                const bhalf8 af = *reinterpret_cast<const bhalf8*>(&W2s[(ct * 16 + ln) * LSTR + k0]);
                acc0[ct] = __builtin_amdgcn_mfma_f32_16x16x32_bf16(af, bf0, acc0[ct], 0, 0, 0);
                acc1[ct] = __builtin_amdgcn_mfma_f32_16x16x32_bf16(af, bf1, acc1[ct], 0, 0, 0);
            }
        }
    }

    // epilogue: y2 = (acc + AqB[i'] + Ak[j])*s2 + u2; conv3 taps reduced over c
    const int jA = j0 + wv * 32 + ln;
    const int jB = jA + 16;
    float z0a = 0.f, z1a = 0.f, z0b = 0.f, z1b = 0.f;
    const float* aqrow = AqB + (size_t)(b * SH + ip) * CK;
    const float* akrA = Ak + (size_t)(b * S + jA) * CK;
    const float* akrB = Ak + (size_t)(b * S + jB) * CK;
    #pragma unroll
    for (int ct = 0; ct < 7; ++ct) {
        const int c = ct * 16 + (quad << 2);
        const float4 aq  = *reinterpret_cast<const float4*>(aqrow + c);
        const float4 aka = *reinterpret_cast<const float4*>(akrA + c);
        const float4 akb = *reinterpret_cast<const float4*>(akrB + c);
        const float4 s2  = *reinterpret_cast<const float4*>(S2 + c);
        const float4 u2  = *reinterpret_cast<const float4*>(U2 + c);
        const float4 w0  = *reinterpret_cast<const float4*>(W30f + c);
        const float4 w1  = *reinterpret_cast<const float4*>(W31f + c);
        const float aqv[4] = {aq.x, aq.y, aq.z, aq.w};
        const float kav[4] = {aka.x, aka.y, aka.z, aka.w};
        const float kbv[4] = {akb.x, akb.y, akb.z, akb.w};
        const float s2v[4] = {s2.x, s2.y, s2.z, s2.w};
        const float u2v[4] = {u2.x, u2.y, u2.z, u2.w};
        const float w0v[4] = {w0.x, w0.y, w0.z, w0.w};
        const float w1v[4] = {w1.x, w1.y, w1.z, w1.w};
        #pragma unroll
        for (int r = 0; r < 4; ++r) {
            float ta = fmaxf(fmaf(acc0[ct][r] + aqv[r] + kav[r], s2v[r], u2v[r]), 0.f);
            z0a = fmaf(ta, w0v[r], z0a);
            z1a = fmaf(ta, w1v[r], z1a);
            float tb = fmaxf(fmaf(acc1[ct][r] + aqv[r] + kbv[r], s2v[r], u2v[r]), 0.f);
            z0b = fmaf(tb, w0v[r], z0b);
            z1b = fmaf(tb, w1v[r], z1b);
        }
    }
    z0a += __shfl_xor(z0a, 16, 64); z0a += __shfl_xor(z0a, 32, 64);
    z1a += __shfl_xor(z1a, 16, 64); z1a += __shfl_xor(z1a, 32, 64);
    z0b += __shfl_xor(z0b, 16, 64); z0b += __shfl_xor(z0b, 32, 64);
    z1b += __shfl_xor(z1b, 16, 64); z1b += __shfl_xor(z1b, 32, 64);
    if (lane < 16) {
        size_t zi = (size_t)(b * SH + ip) * S + j0 + wv * 32 + lane;
        Z0[zi] = z0a; Z1[zi] = z1a;
        Z0[zi + 16] = z0b; Z1[zi + 16] = z1b;
    }
}

// ---------------- K4: logits -> softmax(j) -> attn out + attn@v ----------------
__global__ __launch_bounds__(256) void k_soft(const float* __restrict__ Z0, const float* __restrict__ Z1,
                                              const float* __restrict__ v,
                                              const float* __restrict__ b3,
                                              float* __restrict__ outp,
                                              float* __restrict__ attnp) {
    __shared__ float attn_s[256];
    __shared__ float red[256];
    __shared__ float sred[4];
    const int tid = threadIdx.x, wv = tid >> 6, lane = tid & 63;
    const int i = blockIdx.x, b = blockIdx.y;
    const float b3f = b3[0];
    const size_t zr = (size_t)(b * SH + i) * S;
    float lv = (Z0[zr + tid] + Z1[zr + S + tid] + b3f) * 0.1f;   // Z1 row i+1; /TEMP

    float mx = lv;
    #pragma unroll
    for (int o = 32; o; o >>= 1) mx = fmaxf(mx, __shfl_xor(mx, o, 64));
    if (lane == 0) sred[wv] = mx;
    __syncthreads();
    mx = fmaxf(fmaxf(sred[0], sred[1]), fmaxf(sred[2], sred[3]));
    __syncthreads();
    float e = __expf(lv - mx);
    float sm = e;
    #pragma unroll
    for (int o = 32; o; o >>= 1) sm += __shfl_xor(sm, o, 64);
    if (lane == 0) sred[wv] = sm;
    __syncthreads();
    sm = sred[0] + sred[1] + sred[2] + sred[3];
    float attn = e / sm;
    attnp[(size_t)(b * SO + i) * S + tid] = attn;
    attn_s[tid] = attn;
    __syncthreads();

    const float* vb = v + (size_t)b * S * T;
    float acc = 0.f;
    #pragma unroll 4
    for (int jj = 0; jj < 64; ++jj) {
        int jg = (wv << 6) + jj;
        acc = fmaf(attn_s[jg], vb[jg * T + lane], acc);
    }
    red[tid] = acc;
    __syncthreads();
    if (tid < 64) {
        float o = red[tid] + red[64 + tid] + red[128 + tid] + red[192 + tid];
        outp[(size_t)(b * SO + i) * T + tid] = o;
    }
}

extern "C" void kernel_launch(void* const* d_in, const int* in_sizes, int n_in,
                              void* d_out, int out_size, void* d_ws, size_t ws_size,
                              hipStream_t stream) {
    const float* q    = (const float*)d_in[0];
    const float* kin  = (const float*)d_in[1];
    const float* vin  = (const float*)d_in[2];
    const float* W1   = (const float*)d_in[3];
    const float* b1   = (const float*)d_in[4];
    const float* g1   = (const float*)d_in[5];
    const float* be1  = (const float*)d_in[6];
    const float* m1   = (const float*)d_in[7];
    const float* var1 = (const float*)d_in[8];
    const float* W2   = (const float*)d_in[9];
    const float* b2   = (const float*)d_in[10];
    const float* g2   = (const float*)d_in[11];
    const float* be2  = (const float*)d_in[12];
    const float* m2   = (const float*)d_in[13];
    const float* var2 = (const float*)d_in[14];
    const float* W3   = (const float*)d_in[15];
    const float* b3   = (const float*)d_in[16];

    char* ws = (char*)d_ws;
    float* S1  = (float*)(ws + OFF_S1);
    float* U1  = (float*)(ws + OFF_U1);
    float* S2  = (float*)(ws + OFF_S2);
    float* U2  = (float*)(ws + OFF_U2);
    float* W30 = (float*)(ws + OFF_W30);
    float* W31 = (float*)(ws + OFF_W31);
    float* AqB = (float*)(ws + OFF_AQB);
    float* Akp = (float*)(ws + OFF_AK);
    ush*   W2p = (ush*)(ws + OFF_W2P);
    float* Z0  = (float*)(ws + OFF_Z0);
    float* Z1  = (float*)(ws + OFF_Z1);

    float* outp  = (float*)d_out;
    float* attnp = outp + (size_t)Bb * SO * T;

    k_params<<<1, 128, 0, stream>>>(g1, be1, m1, var1, b2, g2, be2, m2, var2, W3,
                                    S1, U1, S2, U2, W30, W31);
    k_w2pack<<<112, 256, 0, stream>>>(W2, W2p);
    k_aq<<<dim3(SH, Bb), 128, 0, stream>>>(q, W1, b1, AqB);
    k_ak<<<dim3(S, Bb), 128, 0, stream>>>(kin, W1, Akp);
    k_main<<<dim3(2, SH, Bb), 256, 0, stream>>>(AqB, Akp, W2p, S1, U1, S2, U2, W30, W31, Z0, Z1);
    k_soft<<<dim3(SO, Bb), 256, 0, stream>>>(Z0, Z1, vin, b3, outp, attnp);
}

// Round 3
// 221.595 us; speedup vs baseline: 1.2739x; 1.2739x over previous
//
#include <hip/hip_runtime.h>
#include <hip/hip_bf16.h>

typedef float floatx4 __attribute__((ext_vector_type(4)));
typedef short bhalf8  __attribute__((ext_vector_type(8)));
typedef unsigned short ush;
typedef unsigned int uint;

#define EPS 1e-5f

constexpr int Bb = 8, S = 256, T = 64, Dc = 100;
constexpr int SH = 255;   // conv2/y2 rows (S-H+1)
constexpr int SO = 254;   // final logit rows
constexpr int CK = 128;   // padded input-channel (K per h-tap)
constexpr int CR = 112;   // padded output-channel rows (7 x 16)
constexpr int LSTR = 136; // LDS row stride in bf16 (272B): 2-way bank aliasing only (free)

// workspace layout (bytes)
constexpr size_t OFF_U1   = 0;        // f32[128]
constexpr size_t OFF_S2   = 512;      // f32[128]
constexpr size_t OFF_W30  = 1024;     // f32[128]
constexpr size_t OFF_W31  = 1536;     // f32[128]
constexpr size_t OFF_W1T  = 2048;                       // f32 [128][128]
constexpr size_t OFF_W1KT = OFF_W1T + 65536;            // f32 [64][128]
constexpr size_t OFF_W2P  = OFF_W1KT + 32768;           // ush [2][112][128]
constexpr size_t OFF_AQS  = OFF_W2P + 57344;            // f32 [8][255][128]  Aq*s1+u1
constexpr size_t OFF_AQE  = OFF_AQS + (size_t)Bb*SH*CK*4; // f32 [8][255][128]  Aq*s2+u2
constexpr size_t OFF_AKS  = OFF_AQE + (size_t)Bb*SH*CK*4; // f32 [8][256][128]  Ak*s1
constexpr size_t OFF_AKE  = OFF_AKS + (size_t)Bb*S*CK*4;  // f32 [8][256][128]  Ak*s2
constexpr size_t OFF_Z0   = OFF_AKE + (size_t)Bb*S*CK*4;  // f32 [8][255][256]
constexpr size_t OFF_Z1   = OFF_Z0 + (size_t)Bb*SH*S*4;   // f32 [8][255][256]

__device__ __forceinline__ uint pkbf(float lo, float hi) {
    // pack two f32 -> bf16x2 (round-half-up via +0x8000, then take high halves with one v_perm)
    uint a = __float_as_uint(lo) + 0x8000u;
    uint b = __float_as_uint(hi) + 0x8000u;
    return __builtin_amdgcn_perm(b, a, 0x07060302u);
}

// ---------------- prep0: W1 transposes + W2 pack + per-channel params ----------------
__global__ __launch_bounds__(128) void k_prep0(const float* __restrict__ W1, const float* __restrict__ W2,
                                               const float* __restrict__ g1, const float* __restrict__ be1,
                                               const float* __restrict__ m1, const float* __restrict__ var1,
                                               const float* __restrict__ g2, const float* __restrict__ be2,
                                               const float* __restrict__ m2, const float* __restrict__ var2,
                                               const float* __restrict__ b2, const float* __restrict__ W3,
                                               float* __restrict__ W1T, float* __restrict__ W1kT,
                                               ush* __restrict__ W2p,
                                               float* __restrict__ U1, float* __restrict__ S2,
                                               float* __restrict__ W30, float* __restrict__ W31) {
    const int bid = blockIdx.x, tid = threadIdx.x;
    if (bid < 128) {                       // W1T[k][c] = W1[c][k]  (k = 2t+h, first 64 t-rows)
        int k = bid, c = tid;
        W1T[k * 128 + c] = (c < Dc) ? W1[(size_t)c * 256 + k] : 0.f;
    } else if (bid < 192) {                // W1kT[t][c] = W1[c][64+t][0] + W1[c][64+t][1]
        int t = bid - 128, c = tid;
        W1kT[t * 128 + c] = (c < Dc) ? (W1[(size_t)c * 256 + 128 + 2 * t] + W1[(size_t)c * 256 + 129 + 2 * t]) : 0.f;
    } else if (bid < 416) {                // W2 pack -> [h][c(112)][c'(128)] bf16
        int idx = (bid - 192) * 128 + tid;
        int h = idx / (CR * CK);
        int rem = idx % (CR * CK);
        int c = rem / CK, cp = rem % CK;
        float v = (c < Dc && cp < Dc) ? W2[((size_t)c * Dc + cp) * 2 + h] : 0.f;
        __hip_bfloat16 bv = __float2bfloat16(v);
        W2p[idx] = *reinterpret_cast<ush*>(&bv);
    } else {                               // params
        int c = tid;
        float u1 = 0.f, s2 = 0.f, w0 = 0.f, w1 = 0.f;
        if (c < Dc) {
            float sg1 = g1[c] / sqrtf(var1[c] + EPS);
            u1 = be1[c] - m1[c] * sg1;
            s2 = g2[c] / sqrtf(var2[c] + EPS);
            w0 = W3[c * 2 + 0];
            w1 = W3[c * 2 + 1];
        }
        U1[c] = u1; S2[c] = s2; W30[c] = w0; W31[c] = w1;
        (void)b2; (void)be2;
    }
}

// ---------------- prep1: Aq / Ak rows with BN folded (2 variants each) ----------------
__global__ __launch_bounds__(128) void k_prep1(const float* __restrict__ q, const float* __restrict__ kin,
                                               const float* __restrict__ b1,
                                               const float* __restrict__ W1T, const float* __restrict__ W1kT,
                                               const float* __restrict__ g1, const float* __restrict__ be1,
                                               const float* __restrict__ m1, const float* __restrict__ var1,
                                               const float* __restrict__ g2, const float* __restrict__ be2,
                                               const float* __restrict__ m2, const float* __restrict__ var2,
                                               const float* __restrict__ b2,
                                               float* __restrict__ AqS, float* __restrict__ AqE,
                                               float* __restrict__ AkS, float* __restrict__ AkE) {
    __shared__ float xs[128];
    const int bid = blockIdx.x, tid = threadIdx.x;
    const int c = tid;
    float s1 = 0.f, u1 = 0.f, s2 = 0.f, u2 = 0.f;
    if (c < Dc) {
        s1 = g1[c] / sqrtf(var1[c] + EPS);
        u1 = be1[c] - m1[c] * s1;
        s2 = g2[c] / sqrtf(var2[c] + EPS);
        u2 = (b2[c] - m2[c]) * s2 + be2[c];
    }
    if (bid < SH * Bb) {          // Aq row: i = bid % SH, b = bid / SH
        const int i = bid % SH, b = bid / SH;
        if (tid < 64) xs[2 * tid]            = q[((size_t)b * S + i) * T + tid];
        else          xs[2 * (tid - 64) + 1] = q[((size_t)b * S + i + 1) * T + (tid - 64)];
        __syncthreads();
        float s = 0.f;
        #pragma unroll 8
        for (int k = 0; k < 128; ++k) s = fmaf(xs[k], W1T[k * 128 + c], s);
        if (c < Dc) s += b1[c]; else s = 0.f;
        size_t row = ((size_t)b * SH + i) * CK + c;
        AqS[row] = s * s1 + u1;
        AqE[row] = s * s2 + u2;
    } else {                      // Ak row
        const int r = bid - SH * Bb;
        const int j = r % S, b = r / S;
        if (tid < 64) xs[tid] = kin[((size_t)b * S + j) * T + tid];
        __syncthreads();
        float s = 0.f;
        #pragma unroll 8
        for (int t = 0; t < 64; ++t) s = fmaf(xs[t], W1kT[t * 128 + c], s);
        size_t row = ((size_t)b * S + j) * CK + c;
        AkS[row] = s * s1;
        AkE[row] = s * s2;
    }
}

// ---------------- main: per-lane y1 frags -> MFMA conv2 -> fused bn2/relu/conv3 taps ----------------
__global__ __launch_bounds__(256, 4) void k_main(const float* __restrict__ AqS, const float* __restrict__ AkS,
                                                 const float* __restrict__ AqE, const float* __restrict__ AkE,
                                                 const ush* __restrict__ W2p,
                                                 const float* __restrict__ U1, const float* __restrict__ S2,
                                                 const float* __restrict__ W30f, const float* __restrict__ W31f,
                                                 float* __restrict__ Z0, float* __restrict__ Z1) {
    __shared__ __align__(16) ush W2s[CR * LSTR];   // W2[c][c'] for current h (~30 KB)
    const int tid = threadIdx.x;
    const int wv = tid >> 6, lane = tid & 63, ln = lane & 15, quad = lane >> 4;
    const int jt = blockIdx.x, ip = blockIdx.y, b = blockIdx.z;
    const int j0 = jt << 7;
    const int jA = j0 + wv * 32 + ln;
    const int jB = jA + 16;

    floatx4 acc0[7], acc1[7];
    #pragma unroll
    for (int ct = 0; ct < 7; ++ct) {
        acc0[ct] = (floatx4){0.f, 0.f, 0.f, 0.f};
        acc1[ct] = (floatx4){0.f, 0.f, 0.f, 0.f};
    }

    const float* akrA = AkS + (size_t)(b * S + jA) * CK;
    const float* akrB = AkS + (size_t)(b * S + jB) * CK;

    for (int h = 0; h < 2; ++h) {
        __syncthreads();
        for (int idx = tid; idx < CR * 16; idx += 256) {   // stage W2 half (coalesced 16B)
            int row = idx >> 4, ch = idx & 15;
            *reinterpret_cast<uint4*>(&W2s[row * LSTR + ch * 8]) =
                *reinterpret_cast<const uint4*>(&W2p[(h * CR + row) * CK + ch * 8]);
        }
        __syncthreads();
        const int i2 = ip + h;
        const bool zrow = (i2 == 0);
        const float* aqrow = zrow ? U1 : (AqS + (size_t)(b * SH + (i2 - 1)) * CK);
        #pragma unroll
        for (int ks = 0; ks < 4; ++ks) {
            const int k0 = ks * 32 + quad * 8;
            const float4 qa = *reinterpret_cast<const float4*>(aqrow + k0);
            const float4 qb = *reinterpret_cast<const float4*>(aqrow + k0 + 4);
            bhalf8 bf0, bf1;
            if (zrow) {
                uint4 p;
                p.x = pkbf(fmaxf(qa.x, 0.f), fmaxf(qa.y, 0.f));
                p.y = pkbf(fmaxf(qa.z, 0.f), fmaxf(qa.w, 0.f));
                p.z = pkbf(fmaxf(qb.x, 0.f), fmaxf(qb.y, 0.f));
                p.w = pkbf(fmaxf(qb.z, 0.f), fmaxf(qb.w, 0.f));
                bf0 = *reinterpret_cast<bhalf8*>(&p);
                bf1 = bf0;
            } else {
                const float4 ka = *reinterpret_cast<const float4*>(akrA + k0);
                const float4 kb = *reinterpret_cast<const float4*>(akrA + k0 + 4);
                uint4 p;
                p.x = pkbf(fmaxf(qa.x + ka.x, 0.f), fmaxf(qa.y + ka.y, 0.f));
                p.y = pkbf(fmaxf(qa.z + ka.z, 0.f), fmaxf(qa.w + ka.w, 0.f));
                p.z = pkbf(fmaxf(qb.x + kb.x, 0.f), fmaxf(qb.y + kb.y, 0.f));
                p.w = pkbf(fmaxf(qb.z + kb.z, 0.f), fmaxf(qb.w + kb.w, 0.f));
                bf0 = *reinterpret_cast<bhalf8*>(&p);
                const float4 kc = *reinterpret_cast<const float4*>(akrB + k0);
                const float4 kd = *reinterpret_cast<const float4*>(akrB + k0 + 4);
                uint4 r;
                r.x = pkbf(fmaxf(qa.x + kc.x, 0.f), fmaxf(qa.y + kc.y, 0.f));
                r.y = pkbf(fmaxf(qa.z + kc.z, 0.f), fmaxf(qa.w + kc.w, 0.f));
                r.z = pkbf(fmaxf(qb.x + kd.x, 0.f), fmaxf(qb.y + kd.y, 0.f));
                r.w = pkbf(fmaxf(qb.z + kd.z, 0.f), fmaxf(qb.w + kd.w, 0.f));
                bf1 = *reinterpret_cast<bhalf8*>(&r);
            }
            #pragma unroll
            for (int ct = 0; ct < 7; ++ct) {
                const bhalf8 af = *reinterpret_cast<const bhalf8*>(&W2s[(ct * 16 + ln) * LSTR + k0]);
                acc0[ct] = __builtin_amdgcn_mfma_f32_16x16x32_bf16(af, bf0, acc0[ct], 0, 0, 0);
                acc1[ct] = __builtin_amdgcn_mfma_f32_16x16x32_bf16(af, bf1, acc1[ct], 0, 0, 0);
            }
        }
    }

    // epilogue: ta = relu(acc*s2 + AqE[ip] + AkE[j]); conv3 taps z0/z1 reduced over c
    float z0a = 0.f, z1a = 0.f, z0b = 0.f, z1b = 0.f;
    const float* aqer = AqE + (size_t)(b * SH + ip) * CK;
    const float* akeA = AkE + (size_t)(b * S + jA) * CK;
    const float* akeB = AkE + (size_t)(b * S + jB) * CK;
    #pragma unroll
    for (int ct = 0; ct < 7; ++ct) {
        const int c = ct * 16 + (quad << 2);
        const float4 aq  = *reinterpret_cast<const float4*>(aqer + c);
        const float4 aka = *reinterpret_cast<const float4*>(akeA + c);
        const float4 akb = *reinterpret_cast<const float4*>(akeB + c);
        const float4 s2  = *reinterpret_cast<const float4*>(S2 + c);
        const float4 w0  = *reinterpret_cast<const float4*>(W30f + c);
        const float4 w1  = *reinterpret_cast<const float4*>(W31f + c);
        const float aqv[4] = {aq.x, aq.y, aq.z, aq.w};
        const float kav[4] = {aka.x, aka.y, aka.z, aka.w};
        const float kbv[4] = {akb.x, akb.y, akb.z, akb.w};
        const float s2v[4] = {s2.x, s2.y, s2.z, s2.w};
        const float w0v[4] = {w0.x, w0.y, w0.z, w0.w};
        const float w1v[4] = {w1.x, w1.y, w1.z, w1.w};
        #pragma unroll
        for (int r = 0; r < 4; ++r) {
            float ta = fmaxf(fmaf(acc0[ct][r], s2v[r], aqv[r] + kav[r]), 0.f);
            z0a = fmaf(ta, w0v[r], z0a);
            z1a = fmaf(ta, w1v[r], z1a);
            float tb = fmaxf(fmaf(acc1[ct][r], s2v[r], aqv[r] + kbv[r]), 0.f);
            z0b = fmaf(tb, w0v[r], z0b);
            z1b = fmaf(tb, w1v[r], z1b);
        }
    }
    z0a += __shfl_xor(z0a, 16, 64); z0a += __shfl_xor(z0a, 32, 64);
    z1a += __shfl_xor(z1a, 16, 64); z1a += __shfl_xor(z1a, 32, 64);
    z0b += __shfl_xor(z0b, 16, 64); z0b += __shfl_xor(z0b, 32, 64);
    z1b += __shfl_xor(z1b, 16, 64); z1b += __shfl_xor(z1b, 32, 64);
    if (lane < 16) {
        size_t zi = (size_t)(b * SH + ip) * S + j0 + wv * 32 + lane;
        Z0[zi] = z0a; Z1[zi] = z1a;
        Z0[zi + 16] = z0b; Z1[zi + 16] = z1b;
    }
}

// ---------------- softmax + attn@v ----------------
__global__ __launch_bounds__(256) void k_soft(const float* __restrict__ Z0, const float* __restrict__ Z1,
                                              const float* __restrict__ v,
                                              const float* __restrict__ b3,
                                              float* __restrict__ outp,
                                              float* __restrict__ attnp) {
    __shared__ float attn_s[256];
    __shared__ float red[256];
    __shared__ float sred[4];
    const int tid = threadIdx.x, wv = tid >> 6, lane = tid & 63;
    const int i = blockIdx.x, b = blockIdx.y;
    const float b3f = b3[0];
    const size_t zr = (size_t)(b * SH + i) * S;
    float lv = (Z0[zr + tid] + Z1[zr + S + tid] + b3f) * 0.1f;   // Z1 row i+1; /TEMP

    float mx = lv;
    #pragma unroll
    for (int o = 32; o; o >>= 1) mx = fmaxf(mx, __shfl_xor(mx, o, 64));
    if (lane == 0) sred[wv] = mx;
    __syncthreads();
    mx = fmaxf(fmaxf(sred[0], sred[1]), fmaxf(sred[2], sred[3]));
    __syncthreads();
    float e = __expf(lv - mx);
    float sm = e;
    #pragma unroll
    for (int o = 32; o; o >>= 1) sm += __shfl_xor(sm, o, 64);
    if (lane == 0) sred[wv] = sm;
    __syncthreads();
    sm = sred[0] + sred[1] + sred[2] + sred[3];
    float attn = e / sm;
    attnp[(size_t)(b * SO + i) * S + tid] = attn;
    attn_s[tid] = attn;
    __syncthreads();

    const float* vb = v + (size_t)b * S * T;
    float acc = 0.f;
    #pragma unroll 4
    for (int jj = 0; jj < 64; ++jj) {
        int jg = (wv << 6) + jj;
        acc = fmaf(attn_s[jg], vb[jg * T + lane], acc);
    }
    red[tid] = acc;
    __syncthreads();
    if (tid < 64) {
        float o = red[tid] + red[64 + tid] + red[128 + tid] + red[192 + tid];
        outp[(size_t)(b * SO + i) * T + tid] = o;
    }
}

extern "C" void kernel_launch(void* const* d_in, const int* in_sizes, int n_in,
                              void* d_out, int out_size, void* d_ws, size_t ws_size,
                              hipStream_t stream) {
    const float* q    = (const float*)d_in[0];
    const float* kin  = (const float*)d_in[1];
    const float* vin  = (const float*)d_in[2];
    const float* W1   = (const float*)d_in[3];
    const float* b1   = (const float*)d_in[4];
    const float* g1   = (const float*)d_in[5];
    const float* be1  = (const float*)d_in[6];
    const float* m1   = (const float*)d_in[7];
    const float* var1 = (const float*)d_in[8];
    const float* W2   = (const float*)d_in[9];
    const float* b2   = (const float*)d_in[10];
    const float* g2   = (const float*)d_in[11];
    const float* be2  = (const float*)d_in[12];
    const float* m2   = (const float*)d_in[13];
    const float* var2 = (const float*)d_in[14];
    const float* W3   = (const float*)d_in[15];
    const float* b3   = (const float*)d_in[16];

    char* ws = (char*)d_ws;
    float* U1   = (float*)(ws + OFF_U1);
    float* S2p  = (float*)(ws + OFF_S2);
    float* W30  = (float*)(ws + OFF_W30);
    float* W31  = (float*)(ws + OFF_W31);
    float* W1T  = (float*)(ws + OFF_W1T);
    float* W1kT = (float*)(ws + OFF_W1KT);
    ush*   W2p  = (ush*)(ws + OFF_W2P);
    float* AqS  = (float*)(ws + OFF_AQS);
    float* AqE  = (float*)(ws + OFF_AQE);
    float* AkS  = (float*)(ws + OFF_AKS);
    float* AkE  = (float*)(ws + OFF_AKE);
    float* Z0   = (float*)(ws + OFF_Z0);
    float* Z1   = (float*)(ws + OFF_Z1);

    float* outp  = (float*)d_out;
    float* attnp = outp + (size_t)Bb * SO * T;

    k_prep0<<<417, 128, 0, stream>>>(W1, W2, g1, be1, m1, var1, g2, be2, m2, var2, b2, W3,
                                     W1T, W1kT, W2p, U1, S2p, W30, W31);
    k_prep1<<<SH * Bb + S * Bb, 128, 0, stream>>>(q, kin, b1, W1T, W1kT,
                                                  g1, be1, m1, var1, g2, be2, m2, var2, b2,
                                                  AqS, AqE, AkS, AkE);
    k_main<<<dim3(2, SH, Bb), 256, 0, stream>>>(AqS, AkS, AqE, AkE, W2p, U1, S2p, W30, W31, Z0, Z1);
    k_soft<<<dim3(SO, Bb), 256, 0, stream>>>(Z0, Z1, vin, b3, outp, attnp);
}